// Round 10
// baseline (122.557 us; speedup 1.0000x reference)
//
#include <hip/hip_runtime.h>

#define SLOT 2048                 // 128 cells * 16 B (bf16x8), NO x-halo
#define NSLOT 32                  // 32 slots * 2048 = 65536 B LDS exactly

typedef __attribute__((ext_vector_type(8))) short bf16x8;
typedef __attribute__((ext_vector_type(4))) float f32x4;
typedef __attribute__((ext_vector_type(4))) unsigned int u32x4;

static __device__ __forceinline__ unsigned short f2bf_rne(float f) {
    union { float f; unsigned int i; } c; c.f = f;
    unsigned int u = c.i;
    return (unsigned short)((u + 0x7fffu + ((u >> 16) & 1u)) >> 16);
}
static __device__ __forceinline__ unsigned int fbits(float f) {
    union { float f; unsigned int i; } c; c.f = f; return c.i;
}
static __device__ __forceinline__ unsigned int pack_bf16_rne(float lo, float hi) {
    unsigned int ul = fbits(lo), uh = fbits(hi);
    unsigned int tl = ul + 0x7fffu + ((ul >> 16) & 1u);
    unsigned int th = uh + 0x7fffu + ((uh >> 16) & 1u);
    return __builtin_amdgcn_perm(th, tl, 0x07060302u);
}

// LDS-only barrier: ds_write -> ds_read ordering without __syncthreads()'s
// vmcnt(0) drain (stage loads are consumed by ds_write issue; NT stores
// are never re-read).
static __device__ __forceinline__ void barrier_lds_only() {
    asm volatile("s_waitcnt lgkmcnt(0)" ::: "memory");
    __builtin_amdgcn_s_barrier();
    __builtin_amdgcn_sched_barrier(0);
}

struct Frags {
    bf16x8 w1h0, w1h1, w2h;
    f32x4 b1v, b2v;
};

// GEMM1: A = W1^T (bf16 RNE). W1 k-row order: [own | x-1 | x+1 | y-1 | y+1 | z-1 | z+1]
// GEMM2: A2[m=s][k=8q+j] = (j<4) ? W2[4q+j][s] : 0.
static __device__ __forceinline__ void build_frags(
    const float* W1, const float* b1, const float* W2, const float* b2,
    int col, int quad, Frags& F)
{
#pragma unroll
    for (int j = 0; j < 8; ++j) {
        int k0 = quad * 8 + j;
        F.w1h0[j] = (short)f2bf_rne(W1[k0 * 16 + col]);
        int k1 = 32 + quad * 8 + j;
        F.w1h1[j] = (short)f2bf_rne((k1 < 56) ? W1[k1 * 16 + col] : 0.0f);
        float w2 = (j < 4 && col < 8) ? W2[(quad * 4 + j) * 8 + col] : 0.0f;
        F.w2h[j] = (short)f2bf_rne(w2);
    }
#pragma unroll
    for (int r = 0; r < 4; ++r) {
        F.b1v[r] = b1[quad * 4 + r];
        F.b2v[r] = (quad < 2) ? b2[quad * 4 + r] : 0.0f;
    }
}

__global__ __launch_bounds__(64) void setup_kernel(
    const float* __restrict__ W1, const float* __restrict__ b1,
    const float* __restrict__ W2, const float* __restrict__ b2,
    u32x4* __restrict__ ws)
{
    const int lane = threadIdx.x;
    Frags F;
    build_frags(W1, b1, W2, b2, lane & 15, lane >> 4, F);
    union { bf16x8 v; u32x4 u; } c;
    c.v = F.w1h0; ws[0 * 64 + lane] = c.u;
    c.v = F.w1h1; ws[1 * 64 + lane] = c.u;
    c.v = F.w2h;  ws[2 * 64 + lane] = c.u;
    union { f32x4 v; u32x4 u; } b;
    b.v = F.b1v; ws[3 * 64 + lane] = b.u;
    b.v = F.b2v; ws[4 * 64 + lane] = b.u;
}

// ONE-SHOT block: z0..z0+3 x y0..y0+3 x all-x. 1024 blocks, 512 thr (8 waves).
// Slot map (32 x 2048B = 64KB):
//   0..3   : plane z0-1, rows y0..y0+3          (z-neighbor only)
//   4+6p+r : plane z0+p (p=0..3), rows y0-1+r (r=0..5)
//   28..31 : plane z0+4, rows y0..y0+3          (z-neighbor only)
// Schedule: stage all 64 (slot,half) tasks (8/wave) -> ONE LDS barrier ->
// each wave computes 2 (z,row)-steps barrier-free -> exit. r10 rationale:
// M2<=7, M3<=7, M1=18.5, F=33 us/gen across SIX schedules -- the shared
// element was ~9 block-wide barriers/gen amplifying per-wave tail latency
// (all waves burst stores/loads in phase after each barrier; chain of
// barriers accumulates max-jitter). One barrier caps that amplification;
// inter-block overlap (2 blocks/CU, no inter-block coupling) replaces
// intra-block pipelining: block B stages while block A computes.
template<bool USE_WS>
__global__ __launch_bounds__(512, 4) void lattice_kernel(
    const float* __restrict__ states,
    const float* __restrict__ W1, const float* __restrict__ b1,
    const float* __restrict__ W2, const float* __restrict__ b2,
    float* __restrict__ out, const u32x4* __restrict__ ws)
{
    __shared__ __align__(16) unsigned char lds[NSLOT * SLOT];   // 65536 B

    const int tid  = threadIdx.x;
    const int lane = tid & 63;
    const int w    = __builtin_amdgcn_readfirstlane(tid >> 6);   // 0..7, SGPR
    const int col  = lane & 15;
    const int quad = lane >> 4;

    Frags F;
    if (USE_WS) {
        union { u32x4 u; bf16x8 v; } c;
        c.u = ws[0 * 64 + lane]; F.w1h0 = c.v;
        c.u = ws[1 * 64 + lane]; F.w1h1 = c.v;
        c.u = ws[2 * 64 + lane]; F.w2h  = c.v;
        union { u32x4 u; f32x4 v; } b;
        b.u = ws[3 * 64 + lane]; F.b1v = b.v;
        b.u = ws[4 * 64 + lane]; F.b2v = b.v;
    } else {
        build_frags(W1, b1, W2, b2, col, quad, F);
    }

    // XCD swizzle: blockIdx&7 -> 16-z-plane slab (one XCD's L2).
    // inr>>5 = z-subgroup (0..3) within slab; inr&31 = y0/4.
    const int bI   = blockIdx.x;
    const int slab = bI & 7;
    const int inr  = bI >> 3;                    // 0..127
    const int z0   = slab * 16 + ((inr >> 5) << 2);
    const int y0   = (inr & 31) << 2;

    // ---- stage: 64 (slot,half) tasks, 8 per wave, one burst ----
    f32x4 ga[8], gb[8];
#pragma unroll
    for (int i = 0; i < 8; ++i) {
        const int tk = w * 8 + i;                // SALU geometry
        const int s  = tk >> 1, half = tk & 1;
        int zr, yr;
        if (s < 4)       { zr = z0 - 1; yr = y0 + s; }
        else if (s < 28) { const int t = s - 4, p = t / 6, r = t - 6 * p;
                           zr = z0 + p; yr = y0 - 1 + r; }
        else             { zr = z0 + 4; yr = y0 + (s - 28); }
        zr &= 127; yr &= 127;
        const float* g = states + ((size_t)((zr << 14) + (yr << 7) + (half << 6)) << 3);
        ga[i] = *(const f32x4*)(g + (lane << 3));
        gb[i] = *(const f32x4*)(g + (lane << 3) + 4);
    }
#pragma unroll
    for (int i = 0; i < 8; ++i) {
        const int tk = w * 8 + i;
        const int s  = tk >> 1, half = tk & 1;
        u32x4 p;
        p[0] = __builtin_amdgcn_perm(fbits(ga[i][1]), fbits(ga[i][0]), 0x07060302u);
        p[1] = __builtin_amdgcn_perm(fbits(ga[i][3]), fbits(ga[i][2]), 0x07060302u);
        p[2] = __builtin_amdgcn_perm(fbits(gb[i][1]), fbits(gb[i][0]), 0x07060302u);
        p[3] = __builtin_amdgcn_perm(fbits(gb[i][3]), fbits(gb[i][2]), 0x07060302u);
        *(u32x4*)(lds + s * SLOT + ((half * 64 + lane) << 4)) = p;
    }
    barrier_lds_only();                          // the ONLY barrier

    // ---- compute: wave w -> z-step zs = w>>1, rows 2(w&1)+{0,1} ----
    const int zs  = w >> 1;                      // 0..3
    const int Bz  = 4 + 6 * zs;                  // center-plane slot base
    const int zc  = z0 + zs;
    const int dxA = (quad == 1) ? -1 : (quad == 2) ? 1 : 0;
    const int cA  = col + dxA;                   // -1..16; wrapped per-i

#pragma unroll
    for (int j = 0; j < 2; ++j) {
        const int rc    = 2 * (w & 1) + j;       // row_c 0..3
        const int slotA = (quad == 3) ? (Bz + rc) : (Bz + rc + 1);
        int slotB;
        if (quad == 0)      slotB = Bz + rc + 2;                       // y+1
        else if (quad == 1) slotB = (zs == 0) ? rc : (Bz - 6 + rc + 1); // z-1
        else if (quad == 2) slotB = (zs == 3) ? (28 + rc) : (Bz + 6 + rc + 1); // z+1
        else                slotB = Bz + rc + 1;                       // pad (zero wts)
        const unsigned char* pA = lds + slotA * SLOT;
        const unsigned char* pB = lds + slotB * SLOT + (col << 4);
        float* pO = out + (size_t)(((zc << 14) + ((y0 + rc) << 7) + col) * 8 + quad * 4);

        // compute 8 results into distinct regs, then batch NT stores
        f32x4 accs[8];
#pragma unroll
        for (int i = 0; i < 8; ++i) {
            const int cellA = (i * 16 + cA) & 127;         // x periodic wrap
            bf16x8 s0f = *(const bf16x8*)(pA + (cellA << 4));
            bf16x8 s1f = *(const bf16x8*)(pB + (i << 8));

            // GEMM1: D1[hidden][cell], bias in C
            f32x4 acc = F.b1v;
            acc = __builtin_amdgcn_mfma_f32_16x16x32_bf16(F.w1h0, s0f, acc, 0, 0, 0);
            acc = __builtin_amdgcn_mfma_f32_16x16x32_bf16(F.w1h1, s1f, acc, 0, 0, 0);

            // tanh
            float h0t, h1t, h2t, h3t;
            {
                float e;
                e = __expf(2.0f * acc[0]); h0t = 1.0f - 2.0f * __builtin_amdgcn_rcpf(e + 1.0f);
                e = __expf(2.0f * acc[1]); h1t = 1.0f - 2.0f * __builtin_amdgcn_rcpf(e + 1.0f);
                e = __expf(2.0f * acc[2]); h2t = 1.0f - 2.0f * __builtin_amdgcn_rcpf(e + 1.0f);
                e = __expf(2.0f * acc[3]); h3t = 1.0f - 2.0f * __builtin_amdgcn_rcpf(e + 1.0f);
            }
            union { bf16x8 v; unsigned int u[4]; } hf;
            hf.u[0] = pack_bf16_rne(h0t, h1t);
            hf.u[1] = pack_bf16_rne(h2t, h3t);
            hf.u[2] = 0u;
            hf.u[3] = 0u;

            // GEMM2: D2[s][cell], bias in C
            f32x4 a2 = F.b2v;
            a2 = __builtin_amdgcn_mfma_f32_16x16x32_bf16(F.w2h, hf.v, a2, 0, 0, 0);
            accs[i] = a2;
        }
        if (quad < 2) {
#pragma unroll
            for (int i = 0; i < 8; ++i) {
                __builtin_nontemporal_store(accs[i], (f32x4*)(pO + (i << 7)));
            }
        }
    }
}

extern "C" void kernel_launch(void* const* d_in, const int* in_sizes, int n_in,
                              void* d_out, int out_size, void* d_ws, size_t ws_size,
                              hipStream_t stream) {
    const float* states = (const float*)d_in[0];
    const float* W1     = (const float*)d_in[1];
    const float* b1     = (const float*)d_in[2];
    const float* W2     = (const float*)d_in[3];
    const float* b2     = (const float*)d_in[4];
    float* out          = (float*)d_out;

    const bool use_ws = ws_size >= (size_t)(5 * 64 * 16);
    if (use_ws) {
        hipLaunchKernelGGL(setup_kernel, dim3(1), dim3(64), 0, stream,
                           W1, b1, W2, b2, (u32x4*)d_ws);
        hipLaunchKernelGGL((lattice_kernel<true>), dim3(1024), dim3(512), 0, stream,
                           states, W1, b1, W2, b2, out, (const u32x4*)d_ws);
    } else {
        hipLaunchKernelGGL((lattice_kernel<false>), dim3(1024), dim3(512), 0, stream,
                           states, W1, b1, W2, b2, out, (const u32x4*)d_ws);
    }
}